// Round 9
// baseline (212.125 us; speedup 1.0000x reference)
//
#include <hip/hip_runtime.h>
#include <stdint.h>

#define D_DIM 1024
#define NA_DIM 4096
#define NV_DIM 4096

typedef __bf16 bf16_t;
typedef __bf16 bf16x8 __attribute__((ext_vector_type(8)));
typedef float f32x4 __attribute__((ext_vector_type(4)));

// async global->LDS, 16B per lane; LDS base must be wave-uniform (HW adds lane*16)
__device__ __forceinline__ void gload_lds16(const void* g, void* lds) {
  __builtin_amdgcn_global_load_lds(
      (const __attribute__((address_space(1))) unsigned int*)g,
      (__attribute__((address_space(3))) unsigned int*)lds, 16, 0, 0);
}

// ============ 256x256 GEMM core, 2 phases/tile, 32 MFMA/phase ============
// C[m][n] = sum_k A[m][k]*B[n][k], k in [kb, kb+klen). 512 threads = 8 waves (2M x 4N),
// per-wave output 128x64 = 8x4 fragments of mfma_f32_16x16x32_bf16. BK=64 per tile.
// LDS: 128 KiB = 2 buf x {A,B} x 2 half-tiles (128 rows x 64 k bf16) -> 1 block/CU.
// T2 swizzle (both-sides involution, 16B chunk ^= row&7): conflicts measured 0 (r2/r6/r8).
// WHY 2 phases (r8 post-mortem): overhead is ~constant per phase (~630 cyc: barrier sync
// + post-barrier lgkm dead time + addressing), while MFMA pipe demand per phase is what
// we choose. r6/r8 at 16 MFMA/phase: 620/(620+630)=43% MfmaUtil. 32 MFMA/phase doubles
// pipe demand per overhead quantum -> predicted ~60%.
// Phase A (quadrants 0,1): read B-frags(8)+A-frags(8); stage A(T+1) halves 0,1 -> buf P^1;
//   BAR; lgkm(0); SB0; 32 MFMA; BAR.
// Phase B (quadrants 2,3): read A-frags(8); stage B(T+2) halves 0,1 -> buf P;
//   vmcnt(4) (tail: 0); BAR; lgkm(0); SB0; 32 MFMA; BAR.
// vmcnt: steady-state queue at phase B wait = [A(T+1) x4, B(T+2) x4]; VMW(4) leaves
// B(T+2) in flight, forces A(T+1),B(T+1) landed (needed by tile T+1 phase A, guarantee
// crosses waves via the following s_barrier). Tail (T+2>=NT): VMW(0).
// WAR: A-slots of buf P^1 last read in tile T-1 phase B (lgkm(0) before its trailing
// barrier); staged in tile T phase A after that barrier. B-slots of buf P last read in
// tile T phase A; staged in phase B after phase A's trailing barrier. Exact, not timing.
// __launch_bounds__(512,1): r7/r8's (512,2) capped the allocator at 128 VGPR (r7 spilled
// ~9MB/dispatch under it). LDS already limits to 1 block/CU, so 256-VGPR budget is free.
#define VMW(N) asm volatile("s_waitcnt vmcnt(" #N ")" ::: "memory")
#define LKW(N) asm volatile("s_waitcnt lgkmcnt(" #N ")" ::: "memory")
#define SB0() __builtin_amdgcn_sched_barrier(0)
#define BAR() asm volatile("s_barrier" ::: "memory")

__device__ __forceinline__ void gemm256_2ph(const bf16_t* __restrict__ A,
                                            const bf16_t* __restrict__ B,
                                            int K, int kb, int klen, int bm, int bn,
                                            bf16_t* lds, f32x4 acc[8][4]) {
  const int tid = threadIdx.x;
  const int lane = tid & 63;
  const int wid = tid >> 6;
  const int wm = wid >> 2;   // 0..1 : wave row-half (128 rows)
  const int wn = wid & 3;    // 0..3 : wave col-quarter (64 cols)
  const int frow = lane & 15;
  const int hi = lane >> 4;
  const int k0e = ((hi ^ (frow & 7)) << 3);   // swizzled k-chunk (elems); ks=1: ^32

  // staging source (pre-swizzled): lane -> row (lane>>3), logical chunk (lane&7)^(lane>>3)
  const int sr = (wid << 4) + (lane >> 3);              // 0..127 within half-tile
  const int sc = (((lane & 7) ^ (lane >> 3)) << 3);     // source col elems within 64
  const bf16_t* pAs = A + (size_t)(bm + sr) * K + kb + sc;
  const bf16_t* pBs = B + (size_t)(bn + sr) * K + kb + sc;
  const int dstW = wid << 10;                            // wave's 1024-elem LDS stripe

  // fragment read bases (elems): + buf*32768; A half = wm, B half = wn>>1 (+ (wn&1)*64 rows)
  const int aBase = (wm << 13) + frow * 64 + k0e;
  const int bBase = 16384 + ((wn >> 1) << 13) + ((wn & 1) << 12) + frow * 64 + k0e;

#define STG_A(kt, h, bufb) do { \
    const bf16_t* s_ = pAs + (size_t)((h) * 128) * K + (size_t)(kt) * 64; \
    bf16_t* d_ = lds + (bufb) * 32768 + (h) * 8192 + dstW; \
    gload_lds16(s_, d_); gload_lds16(s_ + (size_t)8 * K, d_ + 512); } while (0)
#define STG_B(kt, h, bufb) do { \
    const bf16_t* s_ = pBs + (size_t)((h) * 128) * K + (size_t)(kt) * 64; \
    bf16_t* d_ = lds + (bufb) * 32768 + 16384 + (h) * 8192 + dstW; \
    gload_lds16(s_, d_); gload_lds16(s_ + (size_t)8 * K, d_ + 512); } while (0)

  bf16x8 aF[8];     // A frags: two quadrants of the current phase
  bf16x8 bF[4][2];  // B frags for current tile (read at phase A, live through phase B)

#define READ_A2(Q0, BUFB) do { const bf16_t* Lb_ = lds + (BUFB) * 32768; \
    aF[0] = *(const bf16x8*)&Lb_[aBase + (Q0) * 2048]; \
    aF[1] = *(const bf16x8*)&Lb_[(aBase ^ 32) + (Q0) * 2048]; \
    aF[2] = *(const bf16x8*)&Lb_[aBase + (Q0) * 2048 + 1024]; \
    aF[3] = *(const bf16x8*)&Lb_[(aBase ^ 32) + (Q0) * 2048 + 1024]; \
    aF[4] = *(const bf16x8*)&Lb_[aBase + ((Q0) + 1) * 2048]; \
    aF[5] = *(const bf16x8*)&Lb_[(aBase ^ 32) + ((Q0) + 1) * 2048]; \
    aF[6] = *(const bf16x8*)&Lb_[aBase + ((Q0) + 1) * 2048 + 1024]; \
    aF[7] = *(const bf16x8*)&Lb_[(aBase ^ 32) + ((Q0) + 1) * 2048 + 1024]; } while (0)
#define READ_B(BUFB) do { const bf16_t* Lb_ = lds + (BUFB) * 32768; \
    _Pragma("unroll") for (int fc = 0; fc < 4; ++fc) { \
      bF[fc][0] = *(const bf16x8*)&Lb_[bBase + fc * 1024]; \
      bF[fc][1] = *(const bf16x8*)&Lb_[(bBase ^ 32) + fc * 1024]; } } while (0)

#define MFMA32(Q0) do { \
    __builtin_amdgcn_s_setprio(1); \
    _Pragma("unroll") for (int fc = 0; fc < 4; ++fc) { \
      acc[(Q0) * 2][fc]     = __builtin_amdgcn_mfma_f32_16x16x32_bf16(aF[0], bF[fc][0], acc[(Q0) * 2][fc], 0, 0, 0); \
      acc[(Q0) * 2][fc]     = __builtin_amdgcn_mfma_f32_16x16x32_bf16(aF[1], bF[fc][1], acc[(Q0) * 2][fc], 0, 0, 0); \
      acc[(Q0) * 2 + 1][fc] = __builtin_amdgcn_mfma_f32_16x16x32_bf16(aF[2], bF[fc][0], acc[(Q0) * 2 + 1][fc], 0, 0, 0); \
      acc[(Q0) * 2 + 1][fc] = __builtin_amdgcn_mfma_f32_16x16x32_bf16(aF[3], bF[fc][1], acc[(Q0) * 2 + 1][fc], 0, 0, 0); \
      acc[(Q0) * 2 + 2][fc] = __builtin_amdgcn_mfma_f32_16x16x32_bf16(aF[4], bF[fc][0], acc[(Q0) * 2 + 2][fc], 0, 0, 0); \
      acc[(Q0) * 2 + 2][fc] = __builtin_amdgcn_mfma_f32_16x16x32_bf16(aF[5], bF[fc][1], acc[(Q0) * 2 + 2][fc], 0, 0, 0); \
      acc[(Q0) * 2 + 3][fc] = __builtin_amdgcn_mfma_f32_16x16x32_bf16(aF[6], bF[fc][0], acc[(Q0) * 2 + 3][fc], 0, 0, 0); \
      acc[(Q0) * 2 + 3][fc] = __builtin_amdgcn_mfma_f32_16x16x32_bf16(aF[7], bF[fc][1], acc[(Q0) * 2 + 3][fc], 0, 0, 0); \
    } \
    __builtin_amdgcn_s_setprio(0); } while (0)

// one BK=64 tile: 2 phases, constant buf parity P
#define TILE(P, T) do { \
    const bool mA = ((T) + 1 < NT); \
    const bool mB = ((T) + 2 < NT); \
    /* phase A: quadrants 0,1 */ \
    READ_B(P); READ_A2(0, P); \
    if (mA) { STG_A((T) + 1, 0, (P) ^ 1); STG_A((T) + 1, 1, (P) ^ 1); } \
    BAR(); LKW(0); SB0(); MFMA32(0); BAR(); \
    /* phase B: quadrants 2,3 */ \
    READ_A2(2, P); \
    if (mB) { STG_B((T) + 2, 0, P); STG_B((T) + 2, 1, P); } \
    if (mB) { VMW(4); } else { VMW(0); } \
    BAR(); LKW(0); SB0(); MFMA32(2); BAR(); \
  } while (0)

  const int NT = klen >> 6;   // BK=64 tiles (NT even: 16 or 32)

  // prologue: tile0 {B,A} -> buf0, tile1 {B} -> buf1 (issue order matches steady state)
  STG_B(0, 0, 0); STG_B(0, 1, 0); STG_A(0, 0, 0); STG_A(0, 1, 0);
  STG_B(1, 0, 1); STG_B(1, 1, 1);
  VMW(4);          // tile0 A,B landed; B(1) in flight
  BAR();           // cross-wave visibility of tile0 staging

  for (int it = 0; it < (NT >> 1); ++it) {
    TILE(0, 2 * it);
    TILE(1, 2 * it + 1);
  }
  VMW(0);  // drain before LDS dealloc / block exit
#undef TILE
#undef MFMA32
#undef READ_A2
#undef READ_B
#undef STG_A
#undef STG_B
}

// epilogue: verified C/D map: col = lane&15, row = (lane>>4)*4 + reg
template <int BF16OUT>
__device__ __forceinline__ void store256(void* Cv, int ldc, int bm, int bn, f32x4 acc[8][4]) {
  const int lane = threadIdx.x & 63;
  const int wid = threadIdx.x >> 6;
  const int wm = wid >> 2, wn = wid & 3;
  const int frow = lane & 15, hi = lane >> 4;
  const int row0 = bm + wm * 128 + hi * 4;
  const int col0 = bn + wn * 64 + frow;
#pragma unroll
  for (int rf = 0; rf < 8; ++rf)
#pragma unroll
    for (int fc = 0; fc < 4; ++fc)
#pragma unroll
      for (int r = 0; r < 4; ++r) {
        size_t idx = (size_t)(row0 + rf * 16 + r) * ldc + (col0 + fc * 16);
        if constexpr (BF16OUT) ((bf16_t*)Cv)[idx] = (bf16_t)acc[rf][fc][r];
        else ((float*)Cv)[idx] = acc[rf][fc][r];
      }
}

// ---------------- batched projections: 4 GEMMs [4096,1024]x[1024,1024]^T, bf16 out ----
__global__ __launch_bounds__(512, 1) void gemm_proj4(
    const bf16_t* __restrict__ Xa, const bf16_t* __restrict__ Xv,
    const bf16_t* __restrict__ W0, const bf16_t* __restrict__ W1,
    const bf16_t* __restrict__ W2, const bf16_t* __restrict__ W3,
    bf16_t* __restrict__ C0, bf16_t* __restrict__ C1,
    bf16_t* __restrict__ C2, bf16_t* __restrict__ C3) {
  __shared__ bf16_t lds[65536];
  const int z = blockIdx.z;
  const bf16_t* A = (z < 2) ? Xa : Xv;
  const bf16_t* B = (z == 0) ? W0 : (z == 1) ? W1 : (z == 2) ? W2 : W3;
  bf16_t* C = (z == 0) ? C0 : (z == 1) ? C1 : (z == 2) ? C2 : C3;
  f32x4 acc[8][4] = {};
  gemm256_2ph(A, B, D_DIM, 0, D_DIM, blockIdx.x * 256, blockIdx.y * 256, lds, acc);
  store256<1>(C, D_DIM, blockIdx.x * 256, blockIdx.y * 256, acc);
}

// ---------------- scores GEMM: [4096,1024]x[4096,1024]^T -> f32 ----------------
__global__ __launch_bounds__(512, 1) void gemm_scores(const bf16_t* __restrict__ A,
                                                      const bf16_t* __restrict__ B,
                                                      float* __restrict__ C) {
  __shared__ bf16_t lds[65536];
  f32x4 acc[8][4] = {};
  gemm256_2ph(A, B, D_DIM, 0, D_DIM, blockIdx.x * 256, blockIdx.y * 256, lds, acc);
  store256<0>(C, NV_DIM, blockIdx.x * 256, blockIdx.y * 256, acc);
}

// ---------------- stage 4/5 batched split-K: z = gemm*2 + split ----------------
__global__ __launch_bounds__(512, 1) void gemm_splitk(
    const bf16_t* __restrict__ alpha, const bf16_t* __restrict__ bvT,
    const bf16_t* __restrict__ alphaT, const bf16_t* __restrict__ aaT,
    float* __restrict__ P) {
  __shared__ bf16_t lds[65536];
  const int z = blockIdx.z;
  const bf16_t* A = (z < 2) ? alpha : alphaT;
  const bf16_t* B = (z < 2) ? bvT : aaT;
  const int kb = (z & 1) * 2048;
  f32x4 acc[8][4] = {};
  gemm256_2ph(A, B, 4096, kb, 2048, blockIdx.x * 256, blockIdx.y * 256, lds, acc);
  store256<0>(P + (size_t)z * NA_DIM * D_DIM, D_DIM, blockIdx.x * 256, blockIdx.y * 256, acc);
}

// ---------------- split-K reduce + residual add: out = P0 + P1 + res ----------------
__global__ __launch_bounds__(256) void reduce_splitk(const float* __restrict__ P,
                                                     const float* __restrict__ resA,
                                                     const float* __restrict__ resV,
                                                     float* __restrict__ out) {
  const int g = blockIdx.y;
  const size_t n = (size_t)NA_DIM * D_DIM;
  size_t i = ((size_t)blockIdx.x * 256 + threadIdx.x) * 4;
  const float* p0 = P + (size_t)g * 2 * n;
  const float* p1 = p0 + n;
  const float* r = g ? resV : resA;
  float4 a = *(const float4*)(p0 + i);
  float4 b = *(const float4*)(p1 + i);
  float4 c = *(const float4*)(r + i);
  float4 o = {a.x + b.x + c.x, a.y + b.y + c.y, a.z + b.z + c.z, a.w + b.w + c.w};
  *(float4*)(out + g * n + i) = o;
}

// ---------------- f32 -> bf16 converts (batched) ----------------
__device__ __forceinline__ void cvt8(const float* in, bf16_t* out, int i) {
  float4 v0 = *(const float4*)(in + i);
  float4 v1 = *(const float4*)(in + i + 4);
  bf16x8 o;
  o[0] = (bf16_t)v0.x; o[1] = (bf16_t)v0.y; o[2] = (bf16_t)v0.z; o[3] = (bf16_t)v0.w;
  o[4] = (bf16_t)v1.x; o[5] = (bf16_t)v1.y; o[6] = (bf16_t)v1.z; o[7] = (bf16_t)v1.w;
  *(bf16x8*)(out + i) = o;
}

__global__ __launch_bounds__(256) void cvt2(const float* __restrict__ inA,
                                            const float* __restrict__ inV,
                                            bf16_t* __restrict__ oA,
                                            bf16_t* __restrict__ oV) {
  const float* in = blockIdx.y ? inV : inA;
  bf16_t* out = blockIdx.y ? oV : oA;
  cvt8(in, out, (blockIdx.x * 256 + threadIdx.x) * 8);
}

__global__ __launch_bounds__(256) void cvt4(const float* __restrict__ i0, const float* __restrict__ i1,
                                            const float* __restrict__ i2, const float* __restrict__ i3,
                                            bf16_t* __restrict__ o0, bf16_t* __restrict__ o1,
                                            bf16_t* __restrict__ o2, bf16_t* __restrict__ o3) {
  const int z = blockIdx.y;
  const float* in = (z == 0) ? i0 : (z == 1) ? i1 : (z == 2) ? i2 : i3;
  bf16_t* out = (z == 0) ? o0 : (z == 1) ? o1 : (z == 2) ? o2 : o3;
  cvt8(in, out, (blockIdx.x * 256 + threadIdx.x) * 8);
}

// ---------------- row softmax: f32 [rows][4096] -> bf16 alpha ----------------
__global__ __launch_bounds__(256) void softmax_rows(const float* __restrict__ S,
                                                    bf16_t* __restrict__ P) {
  const int row = blockIdx.x;
  const int ncol = 4096;
  const float* s = S + (size_t)row * ncol;
  const int base = threadIdx.x * 16;
  float v[16];
  float4* vp = (float4*)v;
#pragma unroll
  for (int q = 0; q < 4; ++q) vp[q] = *(const float4*)(s + base + q * 4);
  float m = v[0];
#pragma unroll
  for (int q = 1; q < 16; ++q) m = fmaxf(m, v[q]);
  for (int off = 32; off; off >>= 1) m = fmaxf(m, __shfl_xor(m, off));
  __shared__ float sm[4], ss[4];
  const int wid = threadIdx.x >> 6, lane = threadIdx.x & 63;
  if (lane == 0) sm[wid] = m;
  __syncthreads();
  m = fmaxf(fmaxf(sm[0], sm[1]), fmaxf(sm[2], sm[3]));
  float sum = 0.f;
#pragma unroll
  for (int q = 0; q < 16; ++q) { v[q] = __expf(v[q] - m); sum += v[q]; }
  for (int off = 32; off; off >>= 1) sum += __shfl_xor(sum, off);
  if (lane == 0) ss[wid] = sum;
  __syncthreads();
  const float inv = 1.0f / (ss[0] + ss[1] + ss[2] + ss[3]);
  bf16x8 o0, o1;
#pragma unroll
  for (int q = 0; q < 8; ++q) { o0[q] = (bf16_t)(v[q] * inv); o1[q] = (bf16_t)(v[q + 8] * inv); }
  bf16_t* p = P + (size_t)row * ncol + base;
  *(bf16x8*)p = o0;
  *(bf16x8*)(p + 8) = o1;
}

// ---------------- bf16 transpose: in[R][C] -> out[C][R], 64x64 LDS tiles ----------------
__global__ __launch_bounds__(256) void transpose_bf16(const bf16_t* __restrict__ in,
                                                      bf16_t* __restrict__ out, int R, int C) {
  __shared__ bf16_t t[64][72];
  const int bx = blockIdx.x * 64;
  const int by = blockIdx.y * 64;
  const int tid = threadIdx.x;
  const int c8 = (tid & 7) * 8;
  const int r = tid >> 3;
#pragma unroll
  for (int rr = 0; rr < 64; rr += 32) {
    bf16x8 v = *(const bf16x8*)(in + (size_t)(by + r + rr) * C + bx + c8);
    *(bf16x8*)&t[r + rr][c8] = v;
  }
  __syncthreads();
#pragma unroll
  for (int rr = 0; rr < 64; rr += 32) {
    bf16x8 v;
#pragma unroll
    for (int q = 0; q < 8; ++q) v[q] = t[c8 + q][r + rr];
    *(bf16x8*)(out + (size_t)(bx + r + rr) * R + by + c8) = v;
  }
}

extern "C" void kernel_launch(void* const* d_in, const int* in_sizes, int n_in,
                              void* d_out, int out_size, void* d_ws, size_t ws_size,
                              hipStream_t stream) {
  (void)in_sizes; (void)n_in; (void)out_size; (void)ws_size;
  const float* inA = (const float*)d_in[0];
  const float* inV = (const float*)d_in[1];
  const float* wBa = (const float*)d_in[2];
  const float* wAa = (const float*)d_in[3];
  const float* wBv = (const float*)d_in[4];
  const float* wAv = (const float*)d_in[5];
  float* out = (float*)d_out;

  // workspace layout (~200 MB; split-K partials alias the dead scores buffer)
  char* w = (char*)d_ws;
  auto take = [&](size_t bytes) { void* p = (void*)w; w += bytes; return p; };
  const size_t XB = (size_t)NA_DIM * D_DIM * 2;   // 8 MB
  const size_t WB = (size_t)D_DIM * D_DIM * 2;    // 2 MB
  bf16_t* XaB = (bf16_t*)take(XB);
  bf16_t* XvB = (bf16_t*)take(XB);
  bf16_t* WBaB = (bf16_t*)take(WB);
  bf16_t* WAaB = (bf16_t*)take(WB);
  bf16_t* WBvB = (bf16_t*)take(WB);
  bf16_t* WAvB = (bf16_t*)take(WB);
  bf16_t* b_a = (bf16_t*)take(XB);
  bf16_t* a_v = (bf16_t*)take(XB);
  bf16_t* a_a = (bf16_t*)take(XB);
  bf16_t* b_v = (bf16_t*)take(XB);
  bf16_t* a_aT = (bf16_t*)take(XB);
  bf16_t* b_vT = (bf16_t*)take(XB);
  float* scores = (float*)take((size_t)NA_DIM * NV_DIM * 4);   // 64 MB (reused for partials)
  bf16_t* alpha = (bf16_t*)take((size_t)NA_DIM * NV_DIM * 2);  // 32 MB
  bf16_t* alphaT = (bf16_t*)take((size_t)NA_DIM * NV_DIM * 2); // 32 MB
  float* P = scores;  // split-K partials (4 x 16 MB), alias: scores dead after softmax

  // converts
  cvt2<<<dim3(NA_DIM * D_DIM / 2048, 2), 256, 0, stream>>>(inA, inV, XaB, XvB);
  cvt4<<<dim3(D_DIM * D_DIM / 2048, 4), 256, 0, stream>>>(wBa, wAa, wAv, wBv,
                                                          WBaB, WAaB, WAvB, WBvB);

  // stage 1: 4 projections, one batched launch (256 blocks = 1/CU)
  gemm_proj4<<<dim3(NA_DIM / 256, D_DIM / 256, 4), 512, 0, stream>>>(
      XaB, XvB, WBaB, WAaB, WAvB, WBvB, b_a, a_a, a_v, b_v);

  // stage 2: scores[i][j] = sum_k b_a[i][k] * a_v[j][k]  (256 blocks)
  gemm_scores<<<dim3(NA_DIM / 256, NV_DIM / 256), 512, 0, stream>>>(b_a, a_v, scores);

  // stage 3: row softmax -> bf16 alpha
  softmax_rows<<<NA_DIM, 256, 0, stream>>>(scores, alpha);

  // transposes for k-major operands
  transpose_bf16<<<dim3(NV_DIM / 64, NA_DIM / 64), 256, 0, stream>>>(alpha, alphaT, NA_DIM, NV_DIM);
  transpose_bf16<<<dim3(D_DIM / 64, NA_DIM / 64), 256, 0, stream>>>(a_a, a_aT, NA_DIM, D_DIM);
  transpose_bf16<<<dim3(D_DIM / 64, NV_DIM / 64), 256, 0, stream>>>(b_v, b_vT, NV_DIM, D_DIM);

  // stages 4+5: batched split-K=2 (256 blocks), then reduce+residual
  gemm_splitk<<<dim3(NA_DIM / 256, D_DIM / 256, 4), 512, 0, stream>>>(
      alpha, b_vT, alphaT, a_aT, P);
  reduce_splitk<<<dim3(NA_DIM * D_DIM / 1024, 2), 256, 0, stream>>>(P, inA, inV, out);
}

// Round 10
// 211.615 us; speedup vs baseline: 1.0024x; 1.0024x over previous
//
#include <hip/hip_runtime.h>
#include <stdint.h>

#define D_DIM 1024
#define NA_DIM 4096
#define NV_DIM 4096

typedef __bf16 bf16_t;
typedef __bf16 bf16x8 __attribute__((ext_vector_type(8)));
typedef float f32x4 __attribute__((ext_vector_type(4)));

// async global->LDS, 16B per lane; LDS base must be wave-uniform (HW adds lane*16)
__device__ __forceinline__ void gload_lds16(const void* g, void* lds) {
  __builtin_amdgcn_global_load_lds(
      (const __attribute__((address_space(1))) unsigned int*)g,
      (__attribute__((address_space(3))) unsigned int*)lds, 16, 0, 0);
}

// ====== 256x256 GEMM core, 4 phases/tile, ds_reads pipelined 1 phase ahead ======
// C[m][n] = sum_k A[m][k]*B[n][k], k in [kb, kb+klen). 512 threads = 8 waves (2M x 4N),
// per-wave output 128x64 = 8x4 fragments of mfma_f32_16x16x32_bf16. BK=64/tile.
// LDS: 128 KiB = 2 buf x {A,B} x 2 half-tiles (128 rows x 64 k bf16) -> 1 block/CU.
// T2 swizzle (both-sides involution, 16B chunk ^= row&7): conflicts measured 0 (r2..r9).
// r9 POST-MORTEM: overhead scales with per-phase ds_read volume, not phase count.
// Per tile per CU: LDS frag reads 192KB @ ~85B/cyc ~= 2260 cyc, MFMA demand 2064 cyc,
// measured 5220 -> reads and MFMA are SERIALIZED by the lgkmcnt(0)-before-MFMA pattern.
// FIX: double-buffered A-frag register sets (aF[2]); phase q issues quadrant q+1's
// reads, waits COUNTED lgkmcnt(4) (retires current operands, leaves newest 4 in
// flight), so phase q's MFMA runs while q+1's reads are outstanding. B-frags read once
// per tile at q0. Only q0 exposes a bunched wait.
// lgkm ledger (in-order retire): q0 issue B(8)+s0(4)+s1(4)=16 out; LKW(4)->B,s0 landed.
//   q1 issue s0'(4): out<=8; LKW(4)->s1 landed. q2 issue s1'(4): out<=8; LKW(4)->s0'
//   landed. q3 no issue; LKW(0)->s1' landed (tile fully drained -> WAR proof below).
// vmcnt (unchanged from r6, verified): stage A(T+1)h0/h1 at q0/q1 -> buf P^1,
//   B(T+2)h0/h1 at q2/q3 -> buf P; queue at q3 = [A(T+1)x4, B(T+2)x4]; VMW(4) forces
//   A(T+1),B(T+1) landed (crosses waves via q3's begin-barrier), keeps B(T+2) in
//   flight; tail VMW(0).
// WAR (exact): A-slots of P^1 last read via s1' (issued q2), drained by q3's LKW(0)
//   before q3's end-barrier; re-staged at next tile's q0 after that barrier. B-slots
//   of P last read at q0 (retired by q0's LKW(4)) >=2 barriers before q2/q3 staging.
// __launch_bounds__(512,1): LDS already caps at 1 block/CU; frees the 256-VGPR budget
//   (r7 spilled under (512,2)'s 128-cap; watch WRITE_SIZE for spill regression).
#define VMW(N) asm volatile("s_waitcnt vmcnt(" #N ")" ::: "memory")
#define LKW(N) asm volatile("s_waitcnt lgkmcnt(" #N ")" ::: "memory")
#define SB0() __builtin_amdgcn_sched_barrier(0)
#define BAR() asm volatile("s_barrier" ::: "memory")

__device__ __forceinline__ void gemm256_pl(const bf16_t* __restrict__ A,
                                           const bf16_t* __restrict__ B,
                                           int K, int kb, int klen, int bm, int bn,
                                           bf16_t* lds, f32x4 acc[8][4]) {
  const int tid = threadIdx.x;
  const int lane = tid & 63;
  const int wid = tid >> 6;
  const int wm = wid >> 2;   // 0..1 : wave row-half (128 rows)
  const int wn = wid & 3;    // 0..3 : wave col-quarter (64 cols)
  const int frow = lane & 15;
  const int hi = lane >> 4;
  const int k0e = ((hi ^ (frow & 7)) << 3);   // swizzled k-chunk (elems); ks=1: ^32

  // staging source (pre-swizzled): lane -> row (lane>>3), logical chunk (lane&7)^(lane>>3)
  const int sr = (wid << 4) + (lane >> 3);              // 0..127 within half-tile
  const int sc = (((lane & 7) ^ (lane >> 3)) << 3);     // source col elems within 64
  const bf16_t* pAs = A + (size_t)(bm + sr) * K + kb + sc;
  const bf16_t* pBs = B + (size_t)(bn + sr) * K + kb + sc;
  const int dstW = wid << 10;                            // wave's 1024-elem LDS stripe

  // fragment read bases (elems): + buf*32768; A half = wm, B half = wn>>1 (+ (wn&1)*64 rows)
  const int aBase = (wm << 13) + frow * 64 + k0e;
  const int bBase = 16384 + ((wn >> 1) << 13) + ((wn & 1) << 12) + frow * 64 + k0e;

#define STG_A(kt, h, bufb) do { \
    const bf16_t* s_ = pAs + (size_t)((h) * 128) * K + (size_t)(kt) * 64; \
    bf16_t* d_ = lds + (bufb) * 32768 + (h) * 8192 + dstW; \
    gload_lds16(s_, d_); gload_lds16(s_ + (size_t)8 * K, d_ + 512); } while (0)
#define STG_B(kt, h, bufb) do { \
    const bf16_t* s_ = pBs + (size_t)((h) * 128) * K + (size_t)(kt) * 64; \
    bf16_t* d_ = lds + (bufb) * 32768 + 16384 + (h) * 8192 + dstW; \
    gload_lds16(s_, d_); gload_lds16(s_ + (size_t)8 * K, d_ + 512); } while (0)

  bf16x8 aF[2][4];  // A frags, two sets alternating per phase (static indices only)
  bf16x8 bF[4][2];  // B frags for current tile (read at q0, live through q3)

#define READ_A(S, Q, BUFB) do { const bf16_t* Lb_ = lds + (BUFB) * 32768; \
    aF[S][0] = *(const bf16x8*)&Lb_[aBase + (Q) * 2048]; \
    aF[S][1] = *(const bf16x8*)&Lb_[(aBase ^ 32) + (Q) * 2048]; \
    aF[S][2] = *(const bf16x8*)&Lb_[aBase + (Q) * 2048 + 1024]; \
    aF[S][3] = *(const bf16x8*)&Lb_[(aBase ^ 32) + (Q) * 2048 + 1024]; } while (0)
#define READ_B(BUFB) do { const bf16_t* Lb_ = lds + (BUFB) * 32768; \
    _Pragma("unroll") for (int fc = 0; fc < 4; ++fc) { \
      bF[fc][0] = *(const bf16x8*)&Lb_[bBase + fc * 1024]; \
      bF[fc][1] = *(const bf16x8*)&Lb_[(bBase ^ 32) + fc * 1024]; } } while (0)

#define MFMA16(S, Q) do { \
    __builtin_amdgcn_s_setprio(1); \
    _Pragma("unroll") for (int fc = 0; fc < 4; ++fc) { \
      acc[(Q) * 2][fc]     = __builtin_amdgcn_mfma_f32_16x16x32_bf16(aF[S][0], bF[fc][0], acc[(Q) * 2][fc], 0, 0, 0); \
      acc[(Q) * 2][fc]     = __builtin_amdgcn_mfma_f32_16x16x32_bf16(aF[S][1], bF[fc][1], acc[(Q) * 2][fc], 0, 0, 0); \
      acc[(Q) * 2 + 1][fc] = __builtin_amdgcn_mfma_f32_16x16x32_bf16(aF[S][2], bF[fc][0], acc[(Q) * 2 + 1][fc], 0, 0, 0); \
      acc[(Q) * 2 + 1][fc] = __builtin_amdgcn_mfma_f32_16x16x32_bf16(aF[S][3], bF[fc][1], acc[(Q) * 2 + 1][fc], 0, 0, 0); \
    } \
    __builtin_amdgcn_s_setprio(0); } while (0)

// one BK=64 tile: 4 phases, constant buf parity P; reads pipelined one phase ahead
#define TILE(P, T) do { \
    const bool mA = ((T) + 1 < NT); \
    const bool mB = ((T) + 2 < NT); \
    /* q0: B + A(q0)->s0 + A(q1)->s1; stage A(T+1)h0 */ \
    READ_B(P); READ_A(0, 0, P); READ_A(1, 1, P); \
    if (mA) STG_A((T) + 1, 0, (P) ^ 1); \
    BAR(); LKW(4); SB0(); MFMA16(0, 0); BAR(); \
    /* q1: A(q2)->s0; stage A(T+1)h1 */ \
    READ_A(0, 2, P); \
    if (mA) STG_A((T) + 1, 1, (P) ^ 1); \
    BAR(); LKW(4); SB0(); MFMA16(1, 1); BAR(); \
    /* q2: A(q3)->s1; stage B(T+2)h0 */ \
    READ_A(1, 3, P); \
    if (mB) STG_B((T) + 2, 0, P); \
    BAR(); LKW(4); SB0(); MFMA16(0, 2); BAR(); \
    /* q3: stage B(T+2)h1; counted vmcnt; drain lgkm */ \
    if (mB) { STG_B((T) + 2, 1, P); VMW(4); } else { VMW(0); } \
    BAR(); LKW(0); SB0(); MFMA16(1, 3); BAR(); \
  } while (0)

  const int NT = klen >> 6;   // BK=64 tiles (NT even: 16 or 32)

  // prologue: tile0 {B,A} -> buf0, tile1 {B} -> buf1; establish invariant
  STG_B(0, 0, 0); STG_B(0, 1, 0); STG_A(0, 0, 0); STG_A(0, 1, 0);
  STG_B(1, 0, 1); STG_B(1, 1, 1);
  VMW(4);          // tile0 A,B landed; B(1) in flight
  BAR();           // cross-wave visibility of tile0 staging

  for (int it = 0; it < (NT >> 1); ++it) {
    TILE(0, 2 * it);
    TILE(1, 2 * it + 1);
  }
  VMW(0);  // drain before LDS dealloc / block exit
#undef TILE
#undef MFMA16
#undef READ_A
#undef READ_B
#undef STG_A
#undef STG_B
}

// epilogue: verified C/D map: col = lane&15, row = (lane>>4)*4 + reg
template <int BF16OUT>
__device__ __forceinline__ void store256(void* Cv, int ldc, int bm, int bn, f32x4 acc[8][4]) {
  const int lane = threadIdx.x & 63;
  const int wid = threadIdx.x >> 6;
  const int wm = wid >> 2, wn = wid & 3;
  const int frow = lane & 15, hi = lane >> 4;
  const int row0 = bm + wm * 128 + hi * 4;
  const int col0 = bn + wn * 64 + frow;
#pragma unroll
  for (int rf = 0; rf < 8; ++rf)
#pragma unroll
    for (int fc = 0; fc < 4; ++fc)
#pragma unroll
      for (int r = 0; r < 4; ++r) {
        size_t idx = (size_t)(row0 + rf * 16 + r) * ldc + (col0 + fc * 16);
        if constexpr (BF16OUT) ((bf16_t*)Cv)[idx] = (bf16_t)acc[rf][fc][r];
        else ((float*)Cv)[idx] = acc[rf][fc][r];
      }
}

// ---------------- batched projections: 4 GEMMs [4096,1024]x[1024,1024]^T, bf16 out ----
__global__ __launch_bounds__(512, 1) void gemm_proj4(
    const bf16_t* __restrict__ Xa, const bf16_t* __restrict__ Xv,
    const bf16_t* __restrict__ W0, const bf16_t* __restrict__ W1,
    const bf16_t* __restrict__ W2, const bf16_t* __restrict__ W3,
    bf16_t* __restrict__ C0, bf16_t* __restrict__ C1,
    bf16_t* __restrict__ C2, bf16_t* __restrict__ C3) {
  __shared__ bf16_t lds[65536];
  const int z = blockIdx.z;
  const bf16_t* A = (z < 2) ? Xa : Xv;
  const bf16_t* B = (z == 0) ? W0 : (z == 1) ? W1 : (z == 2) ? W2 : W3;
  bf16_t* C = (z == 0) ? C0 : (z == 1) ? C1 : (z == 2) ? C2 : C3;
  f32x4 acc[8][4] = {};
  gemm256_pl(A, B, D_DIM, 0, D_DIM, blockIdx.x * 256, blockIdx.y * 256, lds, acc);
  store256<1>(C, D_DIM, blockIdx.x * 256, blockIdx.y * 256, acc);
}

// ---------------- scores GEMM: [4096,1024]x[4096,1024]^T -> f32 ----------------
__global__ __launch_bounds__(512, 1) void gemm_scores(const bf16_t* __restrict__ A,
                                                      const bf16_t* __restrict__ B,
                                                      float* __restrict__ C) {
  __shared__ bf16_t lds[65536];
  f32x4 acc[8][4] = {};
  gemm256_pl(A, B, D_DIM, 0, D_DIM, blockIdx.x * 256, blockIdx.y * 256, lds, acc);
  store256<0>(C, NV_DIM, blockIdx.x * 256, blockIdx.y * 256, acc);
}

// ---------------- stage 4/5 batched split-K: z = gemm*2 + split ----------------
__global__ __launch_bounds__(512, 1) void gemm_splitk(
    const bf16_t* __restrict__ alpha, const bf16_t* __restrict__ bvT,
    const bf16_t* __restrict__ alphaT, const bf16_t* __restrict__ aaT,
    float* __restrict__ P) {
  __shared__ bf16_t lds[65536];
  const int z = blockIdx.z;
  const bf16_t* A = (z < 2) ? alpha : alphaT;
  const bf16_t* B = (z < 2) ? bvT : aaT;
  const int kb = (z & 1) * 2048;
  f32x4 acc[8][4] = {};
  gemm256_pl(A, B, 4096, kb, 2048, blockIdx.x * 256, blockIdx.y * 256, lds, acc);
  store256<0>(P + (size_t)z * NA_DIM * D_DIM, D_DIM, blockIdx.x * 256, blockIdx.y * 256, acc);
}

// ---------------- split-K reduce + residual add: out = P0 + P1 + res ----------------
__global__ __launch_bounds__(256) void reduce_splitk(const float* __restrict__ P,
                                                     const float* __restrict__ resA,
                                                     const float* __restrict__ resV,
                                                     float* __restrict__ out) {
  const int g = blockIdx.y;
  const size_t n = (size_t)NA_DIM * D_DIM;
  size_t i = ((size_t)blockIdx.x * 256 + threadIdx.x) * 4;
  const float* p0 = P + (size_t)g * 2 * n;
  const float* p1 = p0 + n;
  const float* r = g ? resV : resA;
  float4 a = *(const float4*)(p0 + i);
  float4 b = *(const float4*)(p1 + i);
  float4 c = *(const float4*)(r + i);
  float4 o = {a.x + b.x + c.x, a.y + b.y + c.y, a.z + b.z + c.z, a.w + b.w + c.w};
  *(float4*)(out + g * n + i) = o;
}

// ---------------- f32 -> bf16 converts (batched) ----------------
__device__ __forceinline__ void cvt8(const float* in, bf16_t* out, int i) {
  float4 v0 = *(const float4*)(in + i);
  float4 v1 = *(const float4*)(in + i + 4);
  bf16x8 o;
  o[0] = (bf16_t)v0.x; o[1] = (bf16_t)v0.y; o[2] = (bf16_t)v0.z; o[3] = (bf16_t)v0.w;
  o[4] = (bf16_t)v1.x; o[5] = (bf16_t)v1.y; o[6] = (bf16_t)v1.z; o[7] = (bf16_t)v1.w;
  *(bf16x8*)(out + i) = o;
}

__global__ __launch_bounds__(256) void cvt2(const float* __restrict__ inA,
                                            const float* __restrict__ inV,
                                            bf16_t* __restrict__ oA,
                                            bf16_t* __restrict__ oV) {
  const float* in = blockIdx.y ? inV : inA;
  bf16_t* out = blockIdx.y ? oV : oA;
  cvt8(in, out, (blockIdx.x * 256 + threadIdx.x) * 8);
}

__global__ __launch_bounds__(256) void cvt4(const float* __restrict__ i0, const float* __restrict__ i1,
                                            const float* __restrict__ i2, const float* __restrict__ i3,
                                            bf16_t* __restrict__ o0, bf16_t* __restrict__ o1,
                                            bf16_t* __restrict__ o2, bf16_t* __restrict__ o3) {
  const int z = blockIdx.y;
  const float* in = (z == 0) ? i0 : (z == 1) ? i1 : (z == 2) ? i2 : i3;
  bf16_t* out = (z == 0) ? o0 : (z == 1) ? o1 : (z == 2) ? o2 : o3;
  cvt8(in, out, (blockIdx.x * 256 + threadIdx.x) * 8);
}

// ---------------- row softmax: f32 [rows][4096] -> bf16 alpha ----------------
__global__ __launch_bounds__(256) void softmax_rows(const float* __restrict__ S,
                                                    bf16_t* __restrict__ P) {
  const int row = blockIdx.x;
  const int ncol = 4096;
  const float* s = S + (size_t)row * ncol;
  const int base = threadIdx.x * 16;
  float v[16];
  float4* vp = (float4*)v;
#pragma unroll
  for (int q = 0; q < 4; ++q) vp[q] = *(const float4*)(s + base + q * 4);
  float m = v[0];
#pragma unroll
  for (int q = 1; q < 16; ++q) m = fmaxf(m, v[q]);
  for (int off = 32; off; off >>= 1) m = fmaxf(m, __shfl_xor(m, off));
  __shared__ float sm[4], ss[4];
  const int wid = threadIdx.x >> 6, lane = threadIdx.x & 63;
  if (lane == 0) sm[wid] = m;
  __syncthreads();
  m = fmaxf(fmaxf(sm[0], sm[1]), fmaxf(sm[2], sm[3]));
  float sum = 0.f;
#pragma unroll
  for (int q = 0; q < 16; ++q) { v[q] = __expf(v[q] - m); sum += v[q]; }
  for (int off = 32; off; off >>= 1) sum += __shfl_xor(sum, off);
  if (lane == 0) ss[wid] = sum;
  __syncthreads();
  const float inv = 1.0f / (ss[0] + ss[1] + ss[2] + ss[3]);
  bf16x8 o0, o1;
#pragma unroll
  for (int q = 0; q < 8; ++q) { o0[q] = (bf16_t)(v[q] * inv); o1[q] = (bf16_t)(v[q + 8] * inv); }
  bf16_t* p = P + (size_t)row * ncol + base;
  *(bf16x8*)p = o0;
  *(bf16x8*)(p + 8) = o1;
}

// ---------------- bf16 transpose: in[R][C] -> out[C][R], 64x64 LDS tiles ----------------
__global__ __launch_bounds__(256) void transpose_bf16(const bf16_t* __restrict__ in,
                                                      bf16_t* __restrict__ out, int R, int C) {
  __shared__ bf16_t t[64][72];
  const int bx = blockIdx.x * 64;
  const int by = blockIdx.y * 64;
  const int tid = threadIdx.x;
  const int c8 = (tid & 7) * 8;
  const int r = tid >> 3;
#pragma unroll
  for (int rr = 0; rr < 64; rr += 32) {
    bf16x8 v = *(const bf16x8*)(in + (size_t)(by + r + rr) * C + bx + c8);
    *(bf16x8*)&t[r + rr][c8] = v;
  }
  __syncthreads();
#pragma unroll
  for (int rr = 0; rr < 64; rr += 32) {
    bf16x8 v;
#pragma unroll
    for (int q = 0; q < 8; ++q) v[q] = t[c8 + q][r + rr];
    *(bf16x8*)(out + (size_t)(bx + r + rr) * R + by + c8) = v;
  }
}

extern "C" void kernel_launch(void* const* d_in, const int* in_sizes, int n_in,
                              void* d_out, int out_size, void* d_ws, size_t ws_size,
                              hipStream_t stream) {
  (void)in_sizes; (void)n_in; (void)out_size; (void)ws_size;
  const float* inA = (const float*)d_in[0];
  const float* inV = (const float*)d_in[1];
  const float* wBa = (const float*)d_in[2];
  const float* wAa = (const float*)d_in[3];
  const float* wBv = (const float*)d_in[4];
  const float* wAv = (const float*)d_in[5];
  float* out = (float*)d_out;

  // workspace layout (~200 MB; split-K partials alias the dead scores buffer)
  char* w = (char*)d_ws;
  auto take = [&](size_t bytes) { void* p = (void*)w; w += bytes; return p; };
  const size_t XB = (size_t)NA_DIM * D_DIM * 2;   // 8 MB
  const size_t WB = (size_t)D_DIM * D_DIM * 2;    // 2 MB
  bf16_t* XaB = (bf16_t*)take(XB);
  bf16_t* XvB = (bf16_t*)take(XB);
  bf16_t* WBaB = (bf16_t*)take(WB);
  bf16_t* WAaB = (bf16_t*)take(WB);
  bf16_t* WBvB = (bf16_t*)take(WB);
  bf16_t* WAvB = (bf16_t*)take(WB);
  bf16_t* b_a = (bf16_t*)take(XB);
  bf16_t* a_v = (bf16_t*)take(XB);
  bf16_t* a_a = (bf16_t*)take(XB);
  bf16_t* b_v = (bf16_t*)take(XB);
  bf16_t* a_aT = (bf16_t*)take(XB);
  bf16_t* b_vT = (bf16_t*)take(XB);
  float* scores = (float*)take((size_t)NA_DIM * NV_DIM * 4);   // 64 MB (reused for partials)
  bf16_t* alpha = (bf16_t*)take((size_t)NA_DIM * NV_DIM * 2);  // 32 MB
  bf16_t* alphaT = (bf16_t*)take((size_t)NA_DIM * NV_DIM * 2); // 32 MB
  float* P = scores;  // split-K partials (4 x 16 MB), alias: scores dead after softmax

  // converts
  cvt2<<<dim3(NA_DIM * D_DIM / 2048, 2), 256, 0, stream>>>(inA, inV, XaB, XvB);
  cvt4<<<dim3(D_DIM * D_DIM / 2048, 4), 256, 0, stream>>>(wBa, wAa, wAv, wBv,
                                                          WBaB, WAaB, WAvB, WBvB);

  // stage 1: 4 projections, one batched launch (256 blocks = 1/CU)
  gemm_proj4<<<dim3(NA_DIM / 256, D_DIM / 256, 4), 512, 0, stream>>>(
      XaB, XvB, WBaB, WAaB, WAvB, WBvB, b_a, a_a, a_v, b_v);

  // stage 2: scores[i][j] = sum_k b_a[i][k] * a_v[j][k]  (256 blocks)
  gemm_scores<<<dim3(NA_DIM / 256, NV_DIM / 256), 512, 0, stream>>>(b_a, a_v, scores);

  // stage 3: row softmax -> bf16 alpha
  softmax_rows<<<NA_DIM, 256, 0, stream>>>(scores, alpha);

  // transposes for k-major operands
  transpose_bf16<<<dim3(NV_DIM / 64, NA_DIM / 64), 256, 0, stream>>>(alpha, alphaT, NA_DIM, NV_DIM);
  transpose_bf16<<<dim3(D_DIM / 64, NA_DIM / 64), 256, 0, stream>>>(a_a, a_aT, NA_DIM, D_DIM);
  transpose_bf16<<<dim3(D_DIM / 64, NV_DIM / 64), 256, 0, stream>>>(b_v, b_vT, NV_DIM, D_DIM);

  // stages 4+5: batched split-K=2 (256 blocks), then reduce+residual
  gemm_splitk<<<dim3(NA_DIM / 256, D_DIM / 256, 4), 512, 0, stream>>>(
      alpha, b_vT, alphaT, a_aT, P);
  reduce_splitk<<<dim3(NA_DIM * D_DIM / 1024, 2), 256, 0, stream>>>(P, inA, inV, out);
}

// Round 11
// 209.740 us; speedup vs baseline: 1.0114x; 1.0089x over previous
//
#include <hip/hip_runtime.h>
#include <stdint.h>

#define D_DIM 1024
#define NA_DIM 4096
#define NV_DIM 4096

typedef __bf16 bf16_t;
typedef __bf16 bf16x8 __attribute__((ext_vector_type(8)));
typedef float f32x4 __attribute__((ext_vector_type(4)));

// async global->LDS, 16B per lane; LDS base must be wave-uniform (HW adds lane*16)
__device__ __forceinline__ void gload_lds16(const void* g, void* lds) {
  __builtin_amdgcn_global_load_lds(
      (const __attribute__((address_space(1))) unsigned int*)g,
      (__attribute__((address_space(3))) unsigned int*)lds, 16, 0, 0);
}

// ====== 256x256 GEMM core, ONE barrier/tile, compiler-interleaved interior ======
// C[m][n] = sum_k A[m][k]*B[n][k], k in [kb, kb+klen). 512 threads = 8 waves (2M x 4N),
// per-wave output 128x64 = 8x4 fragments of mfma_f32_16x16x32_bf16. BK=64/tile.
// LDS: 128 KiB = 2 buf x {A,B} x 2 half-tiles; T2 swizzle (16B chunk ^= row&7, both
// sides) - SQ_LDS_BANK_CONFLICT measured 0 across r2-r10.
// r10 POST-MORTEM: tile time invariant ~5100 cyc across 3 phase schedules = MFMA pipe
// demand (2483/SIMD) + LDS read demand (~2600/CU) SERIALIZED. Cause: per-phase
// [LKW->SB0->MFMA->BAR] fences pin every read outside every MFMA span, so the CU
// alternates read-bursts and MFMA-bursts globally. m97 evidence: hipcc left alone
// interleaves ds_read into the MFMA stream with fine-grained counted lgkmcnt.
// FIX: one barrier per tile; interior = 24 ds_reads + 64 MFMA with NO fences (compiler
// schedules); staging for tile T+1 issued at TOP of tile T (full-tile ~2800 cyc lead
// so the end-of-tile vmcnt(0) is ~free, unlike m97's zero-lead drain).
// Hazards (exact): (a) staging at top of T targets buf P^1, whose last readers (tile
// T-1) drained via LKW(0) before the barrier separating T-1/T; (b) tile T's reads of
// buf P vs tile T+1's staging of P: LKW(0)+BAR between them; (c) vmcnt(0) before BAR
// guarantees buf P^1 landed for tile T+1 across all waves.
#define VMW(N) asm volatile("s_waitcnt vmcnt(" #N ")" ::: "memory")
#define LKW(N) asm volatile("s_waitcnt lgkmcnt(" #N ")" ::: "memory")
#define BAR() asm volatile("s_barrier" ::: "memory")

__device__ __forceinline__ void gemm256_loose(const bf16_t* __restrict__ A,
                                              const bf16_t* __restrict__ B,
                                              int K, int kb, int klen, int bm, int bn,
                                              bf16_t* lds, f32x4 acc[8][4]) {
  const int tid = threadIdx.x;
  const int lane = tid & 63;
  const int wid = tid >> 6;
  const int wm = wid >> 2;   // 0..1 : wave row-half (128 rows)
  const int wn = wid & 3;    // 0..3 : wave col-quarter (64 cols)
  const int frow = lane & 15;
  const int hi = lane >> 4;
  const int k0e = ((hi ^ (frow & 7)) << 3);   // swizzled k-chunk (elems); ks=1: ^32

  // staging source (pre-swizzled): lane -> row (lane>>3), logical chunk (lane&7)^(lane>>3)
  const int sr = (wid << 4) + (lane >> 3);              // 0..127 within half-tile
  const int sc = (((lane & 7) ^ (lane >> 3)) << 3);     // source col elems within 64
  const bf16_t* pAs = A + (size_t)(bm + sr) * K + kb + sc;
  const bf16_t* pBs = B + (size_t)(bn + sr) * K + kb + sc;
  const int dstW = wid << 10;                            // wave's 1024-elem LDS stripe

  // fragment read bases (elems): + buf*32768; A half = wm, B half = wn>>1 (+ (wn&1)*64 rows)
  const int aBase = (wm << 13) + frow * 64 + k0e;
  const int bBase = 16384 + ((wn >> 1) << 13) + ((wn & 1) << 12) + frow * 64 + k0e;

#define STG_A(kt, h, bufb) do { \
    const bf16_t* s_ = pAs + (size_t)((h) * 128) * K + (size_t)(kt) * 64; \
    bf16_t* d_ = lds + (bufb) * 32768 + (h) * 8192 + dstW; \
    gload_lds16(s_, d_); gload_lds16(s_ + (size_t)8 * K, d_ + 512); } while (0)
#define STG_B(kt, h, bufb) do { \
    const bf16_t* s_ = pBs + (size_t)((h) * 128) * K + (size_t)(kt) * 64; \
    bf16_t* d_ = lds + (bufb) * 32768 + 16384 + (h) * 8192 + dstW; \
    gload_lds16(s_, d_); gload_lds16(s_ + (size_t)8 * K, d_ + 512); } while (0)

#define MFMA(a, b, c) __builtin_amdgcn_mfma_f32_16x16x32_bf16((a), (b), (c), 0, 0, 0)

// one BK=64 tile, parity P: stage T+1 at top; loose read+MFMA interior; fences at end.
#define TILE(P, T) do { \
    if ((T) + 1 < NT) { \
      STG_A((T) + 1, 0, (P) ^ 1); STG_A((T) + 1, 1, (P) ^ 1); \
      STG_B((T) + 1, 0, (P) ^ 1); STG_B((T) + 1, 1, (P) ^ 1); \
    } \
    { \
      const bf16_t* Lb_ = lds + (P) * 32768; \
      bf16x8 bf0[4], bf1[4]; \
      _Pragma("unroll") for (int fc = 0; fc < 4; ++fc) { \
        bf0[fc] = *(const bf16x8*)&Lb_[bBase + fc * 1024]; \
        bf1[fc] = *(const bf16x8*)&Lb_[(bBase ^ 32) + fc * 1024]; \
      } \
      _Pragma("unroll") for (int q = 0; q < 4; ++q) { \
        bf16x8 a0 = *(const bf16x8*)&Lb_[aBase + q * 2048]; \
        bf16x8 a1 = *(const bf16x8*)&Lb_[(aBase ^ 32) + q * 2048]; \
        bf16x8 a2 = *(const bf16x8*)&Lb_[aBase + q * 2048 + 1024]; \
        bf16x8 a3 = *(const bf16x8*)&Lb_[(aBase ^ 32) + q * 2048 + 1024]; \
        _Pragma("unroll") for (int fc = 0; fc < 4; ++fc) { \
          acc[q * 2][fc]     = MFMA(a0, bf0[fc], acc[q * 2][fc]); \
          acc[q * 2][fc]     = MFMA(a1, bf1[fc], acc[q * 2][fc]); \
          acc[q * 2 + 1][fc] = MFMA(a2, bf0[fc], acc[q * 2 + 1][fc]); \
          acc[q * 2 + 1][fc] = MFMA(a3, bf1[fc], acc[q * 2 + 1][fc]); \
        } \
      } \
    } \
    LKW(0); VMW(0); BAR(); \
  } while (0)

  const int NT = klen >> 6;   // BK=64 tiles (>= 16, even)

  // prologue: tile0 -> buf0
  STG_A(0, 0, 0); STG_A(0, 1, 0); STG_B(0, 0, 0); STG_B(0, 1, 0);
  VMW(0);
  BAR();

  for (int it = 0; it < (NT >> 1); ++it) {
    TILE(0, 2 * it);
    TILE(1, 2 * it + 1);
  }
#undef TILE
#undef MFMA
#undef STG_A
#undef STG_B
}

// epilogue: verified C/D map: col = lane&15, row = (lane>>4)*4 + reg
template <int BF16OUT>
__device__ __forceinline__ void store256(void* Cv, int ldc, int bm, int bn, f32x4 acc[8][4]) {
  const int lane = threadIdx.x & 63;
  const int wid = threadIdx.x >> 6;
  const int wm = wid >> 2, wn = wid & 3;
  const int frow = lane & 15, hi = lane >> 4;
  const int row0 = bm + wm * 128 + hi * 4;
  const int col0 = bn + wn * 64 + frow;
#pragma unroll
  for (int rf = 0; rf < 8; ++rf)
#pragma unroll
    for (int fc = 0; fc < 4; ++fc)
#pragma unroll
      for (int r = 0; r < 4; ++r) {
        size_t idx = (size_t)(row0 + rf * 16 + r) * ldc + (col0 + fc * 16);
        if constexpr (BF16OUT) ((bf16_t*)Cv)[idx] = (bf16_t)acc[rf][fc][r];
        else ((float*)Cv)[idx] = acc[rf][fc][r];
      }
}

// ---------------- batched projections: 4 GEMMs [4096,1024]x[1024,1024]^T, bf16 out ----
__global__ __launch_bounds__(512, 1) void gemm_proj4(
    const bf16_t* __restrict__ Xa, const bf16_t* __restrict__ Xv,
    const bf16_t* __restrict__ W0, const bf16_t* __restrict__ W1,
    const bf16_t* __restrict__ W2, const bf16_t* __restrict__ W3,
    bf16_t* __restrict__ C0, bf16_t* __restrict__ C1,
    bf16_t* __restrict__ C2, bf16_t* __restrict__ C3) {
  __shared__ bf16_t lds[65536];
  const int z = blockIdx.z;
  const bf16_t* A = (z < 2) ? Xa : Xv;
  const bf16_t* B = (z == 0) ? W0 : (z == 1) ? W1 : (z == 2) ? W2 : W3;
  bf16_t* C = (z == 0) ? C0 : (z == 1) ? C1 : (z == 2) ? C2 : C3;
  f32x4 acc[8][4] = {};
  gemm256_loose(A, B, D_DIM, 0, D_DIM, blockIdx.x * 256, blockIdx.y * 256, lds, acc);
  store256<1>(C, D_DIM, blockIdx.x * 256, blockIdx.y * 256, acc);
}

// ---------------- scores GEMM: [4096,1024]x[4096,1024]^T -> f32 ----------------
__global__ __launch_bounds__(512, 1) void gemm_scores(const bf16_t* __restrict__ A,
                                                      const bf16_t* __restrict__ B,
                                                      float* __restrict__ C) {
  __shared__ bf16_t lds[65536];
  f32x4 acc[8][4] = {};
  gemm256_loose(A, B, D_DIM, 0, D_DIM, blockIdx.x * 256, blockIdx.y * 256, lds, acc);
  store256<0>(C, NV_DIM, blockIdx.x * 256, blockIdx.y * 256, acc);
}

// ---------------- stage 4/5 batched split-K: z = gemm*2 + split ----------------
__global__ __launch_bounds__(512, 1) void gemm_splitk(
    const bf16_t* __restrict__ alpha, const bf16_t* __restrict__ bvT,
    const bf16_t* __restrict__ alphaT, const bf16_t* __restrict__ aaT,
    float* __restrict__ P) {
  __shared__ bf16_t lds[65536];
  const int z = blockIdx.z;
  const bf16_t* A = (z < 2) ? alpha : alphaT;
  const bf16_t* B = (z < 2) ? bvT : aaT;
  const int kb = (z & 1) * 2048;
  f32x4 acc[8][4] = {};
  gemm256_loose(A, B, 4096, kb, 2048, blockIdx.x * 256, blockIdx.y * 256, lds, acc);
  store256<0>(P + (size_t)z * NA_DIM * D_DIM, D_DIM, blockIdx.x * 256, blockIdx.y * 256, acc);
}

// ---------------- split-K reduce + residual add: out = P0 + P1 + res ----------------
__global__ __launch_bounds__(256) void reduce_splitk(const float* __restrict__ P,
                                                     const float* __restrict__ resA,
                                                     const float* __restrict__ resV,
                                                     float* __restrict__ out) {
  const int g = blockIdx.y;
  const size_t n = (size_t)NA_DIM * D_DIM;
  size_t i = ((size_t)blockIdx.x * 256 + threadIdx.x) * 4;
  const float* p0 = P + (size_t)g * 2 * n;
  const float* p1 = p0 + n;
  const float* r = g ? resV : resA;
  float4 a = *(const float4*)(p0 + i);
  float4 b = *(const float4*)(p1 + i);
  float4 c = *(const float4*)(r + i);
  float4 o = {a.x + b.x + c.x, a.y + b.y + c.y, a.z + b.z + c.z, a.w + b.w + c.w};
  *(float4*)(out + g * n + i) = o;
}

// ---------------- f32 -> bf16 converts (batched) ----------------
__device__ __forceinline__ void cvt8(const float* in, bf16_t* out, int i) {
  float4 v0 = *(const float4*)(in + i);
  float4 v1 = *(const float4*)(in + i + 4);
  bf16x8 o;
  o[0] = (bf16_t)v0.x; o[1] = (bf16_t)v0.y; o[2] = (bf16_t)v0.z; o[3] = (bf16_t)v0.w;
  o[4] = (bf16_t)v1.x; o[5] = (bf16_t)v1.y; o[6] = (bf16_t)v1.z; o[7] = (bf16_t)v1.w;
  *(bf16x8*)(out + i) = o;
}

__global__ __launch_bounds__(256) void cvt2(const float* __restrict__ inA,
                                            const float* __restrict__ inV,
                                            bf16_t* __restrict__ oA,
                                            bf16_t* __restrict__ oV) {
  const float* in = blockIdx.y ? inV : inA;
  bf16_t* out = blockIdx.y ? oV : oA;
  cvt8(in, out, (blockIdx.x * 256 + threadIdx.x) * 8);
}

__global__ __launch_bounds__(256) void cvt4(const float* __restrict__ i0, const float* __restrict__ i1,
                                            const float* __restrict__ i2, const float* __restrict__ i3,
                                            bf16_t* __restrict__ o0, bf16_t* __restrict__ o1,
                                            bf16_t* __restrict__ o2, bf16_t* __restrict__ o3) {
  const int z = blockIdx.y;
  const float* in = (z == 0) ? i0 : (z == 1) ? i1 : (z == 2) ? i2 : i3;
  bf16_t* out = (z == 0) ? o0 : (z == 1) ? o1 : (z == 2) ? o2 : o3;
  cvt8(in, out, (blockIdx.x * 256 + threadIdx.x) * 8);
}

// ---------------- row softmax: f32 [rows][4096] -> bf16 alpha ----------------
__global__ __launch_bounds__(256) void softmax_rows(const float* __restrict__ S,
                                                    bf16_t* __restrict__ P) {
  const int row = blockIdx.x;
  const int ncol = 4096;
  const float* s = S + (size_t)row * ncol;
  const int base = threadIdx.x * 16;
  float v[16];
  float4* vp = (float4*)v;
#pragma unroll
  for (int q = 0; q < 4; ++q) vp[q] = *(const float4*)(s + base + q * 4);
  float m = v[0];
#pragma unroll
  for (int q = 1; q < 16; ++q) m = fmaxf(m, v[q]);
  for (int off = 32; off; off >>= 1) m = fmaxf(m, __shfl_xor(m, off));
  __shared__ float sm[4], ss[4];
  const int wid = threadIdx.x >> 6, lane = threadIdx.x & 63;
  if (lane == 0) sm[wid] = m;
  __syncthreads();
  m = fmaxf(fmaxf(sm[0], sm[1]), fmaxf(sm[2], sm[3]));
  float sum = 0.f;
#pragma unroll
  for (int q = 0; q < 16; ++q) { v[q] = __expf(v[q] - m); sum += v[q]; }
  for (int off = 32; off; off >>= 1) sum += __shfl_xor(sum, off);
  if (lane == 0) ss[wid] = sum;
  __syncthreads();
  const float inv = 1.0f / (ss[0] + ss[1] + ss[2] + ss[3]);
  bf16x8 o0, o1;
#pragma unroll
  for (int q = 0; q < 8; ++q) { o0[q] = (bf16_t)(v[q] * inv); o1[q] = (bf16_t)(v[q + 8] * inv); }
  bf16_t* p = P + (size_t)row * ncol + base;
  *(bf16x8*)p = o0;
  *(bf16x8*)(p + 8) = o1;
}

// ---------------- bf16 transpose: in[R][C] -> out[C][R], 64x64 LDS tiles ----------------
__global__ __launch_bounds__(256) void transpose_bf16(const bf16_t* __restrict__ in,
                                                      bf16_t* __restrict__ out, int R, int C) {
  __shared__ bf16_t t[64][72];
  const int bx = blockIdx.x * 64;
  const int by = blockIdx.y * 64;
  const int tid = threadIdx.x;
  const int c8 = (tid & 7) * 8;
  const int r = tid >> 3;
#pragma unroll
  for (int rr = 0; rr < 64; rr += 32) {
    bf16x8 v = *(const bf16x8*)(in + (size_t)(by + r + rr) * C + bx + c8);
    *(bf16x8*)&t[r + rr][c8] = v;
  }
  __syncthreads();
#pragma unroll
  for (int rr = 0; rr < 64; rr += 32) {
    bf16x8 v;
#pragma unroll
    for (int q = 0; q < 8; ++q) v[q] = t[c8 + q][r + rr];
    *(bf16x8*)(out + (size_t)(bx + r + rr) * R + by + c8) = v;
  }
}

extern "C" void kernel_launch(void* const* d_in, const int* in_sizes, int n_in,
                              void* d_out, int out_size, void* d_ws, size_t ws_size,
                              hipStream_t stream) {
  (void)in_sizes; (void)n_in; (void)out_size; (void)ws_size;
  const float* inA = (const float*)d_in[0];
  const float* inV = (const float*)d_in[1];
  const float* wBa = (const float*)d_in[2];
  const float* wAa = (const float*)d_in[3];
  const float* wBv = (const float*)d_in[4];
  const float* wAv = (const float*)d_in[5];
  float* out = (float*)d_out;

  // workspace layout (~200 MB; split-K partials alias the dead scores buffer)
  char* w = (char*)d_ws;
  auto take = [&](size_t bytes) { void* p = (void*)w; w += bytes; return p; };
  const size_t XB = (size_t)NA_DIM * D_DIM * 2;   // 8 MB
  const size_t WB = (size_t)D_DIM * D_DIM * 2;    // 2 MB
  bf16_t* XaB = (bf16_t*)take(XB);
  bf16_t* XvB = (bf16_t*)take(XB);
  bf16_t* WBaB = (bf16_t*)take(WB);
  bf16_t* WAaB = (bf16_t*)take(WB);
  bf16_t* WBvB = (bf16_t*)take(WB);
  bf16_t* WAvB = (bf16_t*)take(WB);
  bf16_t* b_a = (bf16_t*)take(XB);
  bf16_t* a_v = (bf16_t*)take(XB);
  bf16_t* a_a = (bf16_t*)take(XB);
  bf16_t* b_v = (bf16_t*)take(XB);
  bf16_t* a_aT = (bf16_t*)take(XB);
  bf16_t* b_vT = (bf16_t*)take(XB);
  float* scores = (float*)take((size_t)NA_DIM * NV_DIM * 4);   // 64 MB (reused for partials)
  bf16_t* alpha = (bf16_t*)take((size_t)NA_DIM * NV_DIM * 2);  // 32 MB
  bf16_t* alphaT = (bf16_t*)take((size_t)NA_DIM * NV_DIM * 2); // 32 MB
  float* P = scores;  // split-K partials (4 x 16 MB), alias: scores dead after softmax

  // converts
  cvt2<<<dim3(NA_DIM * D_DIM / 2048, 2), 256, 0, stream>>>(inA, inV, XaB, XvB);
  cvt4<<<dim3(D_DIM * D_DIM / 2048, 4), 256, 0, stream>>>(wBa, wAa, wAv, wBv,
                                                          WBaB, WAaB, WAvB, WBvB);

  // stage 1: 4 projections, one batched launch (256 blocks = 1/CU)
  gemm_proj4<<<dim3(NA_DIM / 256, D_DIM / 256, 4), 512, 0, stream>>>(
      XaB, XvB, WBaB, WAaB, WAvB, WBvB, b_a, a_a, a_v, b_v);

  // stage 2: scores[i][j] = sum_k b_a[i][k] * a_v[j][k]  (256 blocks)
  gemm_scores<<<dim3(NA_DIM / 256, NV_DIM / 256), 512, 0, stream>>>(b_a, a_v, scores);

  // stage 3: row softmax -> bf16 alpha
  softmax_rows<<<NA_DIM, 256, 0, stream>>>(scores, alpha);

  // transposes for k-major operands
  transpose_bf16<<<dim3(NV_DIM / 64, NA_DIM / 64), 256, 0, stream>>>(alpha, alphaT, NA_DIM, NV_DIM);
  transpose_bf16<<<dim3(D_DIM / 64, NA_DIM / 64), 256, 0, stream>>>(a_a, a_aT, NA_DIM, D_DIM);
  transpose_bf16<<<dim3(D_DIM / 64, NV_DIM / 64), 256, 0, stream>>>(b_v, b_vT, NV_DIM, D_DIM);

  // stages 4+5: batched split-K=2 (256 blocks), then reduce+residual
  gemm_splitk<<<dim3(NA_DIM / 256, D_DIM / 256, 4), 512, 0, stream>>>(
      alpha, b_vT, alphaT, a_aT, P);
  reduce_splitk<<<dim3(NA_DIM * D_DIM / 1024, 2), 256, 0, stream>>>(P, inA, inV, out);
}